// Round 11
// baseline (1031.452 us; speedup 1.0000x reference)
//
#include <hip/hip_runtime.h>

#define H 181
#define T_LEN 1024
#define BB 4             // batch rows per block
#define NBLK 256         // 256 * 4 = 1024; one block per CU (LDS-pinned)
#define NTHR 768         // 12 waves, 3 per SIMD
#define KT3 3            // k-tiles of 64 -> 192 >= 181
#define FRAGB 1024       // bytes per kt fragment (64 lanes x 16 B)
#define PST 192          // preact / unit stride

typedef __attribute__((ext_vector_type(4))) int   intx4;
typedef __attribute__((ext_vector_type(4))) float floatx4;

#define LOG2E 1.4426950408889634f
// Schraudolph exp2 (balanced sawtooth, |rel err| <= ~3%), clamped to [-20,14]
#define SCH_C  1064992506.0f
#define SCH_LO 897220352.0f
#define SCH_HI 1182433024.0f

__device__ __forceinline__ float exp2_fast(float g) {
    float s = fmaf(g, 8388608.0f, SCH_C);
    s = fminf(fmaxf(s, SCH_LO), SCH_HI);
    return __uint_as_float((unsigned)s);
}
__device__ __forceinline__ float rcpf(float x)   { return __builtin_amdgcn_rcpf(x); }
__device__ __forceinline__ float exp2hw(float x) { return __builtin_amdgcn_exp2f(x); }

// 256 persistent blocks x 4 batch (ALL 256 CUs). Two-phase step:
//  P1 (wave = gate g, 3 unit-tiles): B-frag h (i8, LDS) x A = w_hh (i8 regs)
//     -> 9 mfma_i32_16x16x64_i8 -> dequant (scales/biases/log2e folded)
//     -> b128 preact publish (f32, [g][b][unit]).
//  P2 (lane = ONE (unit,batch) triple, densely packed: b=tid/192, j=tid%192):
//     coalesced preact reads -> 3 exps (r Schraudolph, z/n exact) + 2 rcps
//     -> h update in-reg -> i8 quant -> DPP quad-pack -> one b32/4 lanes
//     into the MFMA B-frag slot.
// Gate exp-instrs/CU/step: 36 vs 144 at BB=16 (the measured VALU wall).
// Pad units (>=H) carry zero A-weights and write 0 to frags.
__launch_bounds__(NTHR, 3)
__global__ void gru_i8(const float* __restrict__ x,
                       const float* __restrict__ w_ih,
                       const float* __restrict__ w_hh,
                       const float* __restrict__ b_ih,
                       const float* __restrict__ b_hh,
                       const float* __restrict__ w_fc,
                       const float* __restrict__ b_fc,
                       float* __restrict__ out) {
    __shared__ __align__(16) char  hfr_s[2 * KT3 * FRAGB];  // 6 KB i8 h dbuf
    __shared__ __align__(16) float pre_s[3 * BB * PST];     // 9 KB preacts
    __shared__ __align__(16) float x_s[BB * T_LEN];         // 16 KB x
    __shared__ float wsc_s[3 * PST];                        // w_hh row scales
    __shared__ volatile char pad_s[54272];                  // LDS>80KB: pin 1 block/CU

    const int tid  = threadIdx.x;
    const int wv   = tid >> 6;
    const int lane = tid & 63;
    const int col  = lane & 15;
    const int q    = lane >> 4;
    const int b0   = blockIdx.x * BB;
    if (tid == 0) pad_s[0] = 0;

    // ================= phase-1 identity: gate g, tile group tg =================
    const int g  = wv >> 2;          // 0..2
    const int tg = wv & 3;           // 0..3 ; tiles tg*3+{0,1,2}
    const float gs = (g < 2) ? -LOG2E : 2.0f * LOG2E;

    // ---- A fragments: per-row int8 w_hh, 3 tiles x 3 kt ----
    intx4 afr[3][KT3];
    #pragma unroll
    for (int u = 0; u < 3; ++u) {
        const int  mu = (tg * 3 + u) * 16 + col;
        const bool mv = (mu < H);
        const float* wrow = w_hh + (size_t)(g * H + (mv ? mu : 0)) * H;
        float rm = 0.0f;
        if (mv) for (int k = 0; k < H; ++k) rm = fmaxf(rm, fabsf(wrow[k]));
        float s    = (rm > 1e-30f) ? rm * (1.0f / 127.0f) : 1.0f;
        float invs = 1.0f / s;
        #pragma unroll
        for (int kt = 0; kt < KT3; ++kt) {
            union { signed char c[16]; intx4 v; } uu;
            #pragma unroll
            for (int e = 0; e < 16; ++e) {
                int k = kt * 64 + q * 16 + e;
                float v = (mv && k < H) ? wrow[k] * invs : 0.0f;
                v = fminf(fmaxf(rintf(v), -127.0f), 127.0f);
                uu.c[e] = (signed char)(int)v;
            }
            afr[u][kt] = uu.v;
        }
        if (q == 0) wsc_s[g * PST + mu] = s;
    }

    // ---- stage x; zero h frag buffers ----
    for (int i = tid; i < BB * T_LEN; i += NTHR)
        x_s[i] = x[(size_t)b0 * T_LEN + i];
    {
        int* hz = (int*)hfr_s;
        for (int i = tid; i < 2 * KT3 * FRAGB / 4; i += NTHR) hz[i] = 0;
    }
    __syncthreads();   // wsc_s ready

    // ---- phase-1 dequant constants (per C-lane: 3 tiles x 4 units) ----
    float dqv[3][4], basev[3][4];
    #pragma unroll
    for (int u = 0; u < 3; ++u)
        #pragma unroll
        for (int r = 0; r < 4; ++r) {
            int unit = (tg * 3 + u) * 16 + q * 4 + r;
            bool uv  = (unit < H);
            dqv[u][r] = gs * wsc_s[g * PST + unit] * (1.0f / 127.0f);
            float bsum;
            if (g == 0)      bsum = uv ? (b_ih[unit] + b_hh[unit]) : 0.0f;
            else if (g == 1) bsum = uv ? (b_ih[H + unit] + b_hh[H + unit]) : 0.0f;
            else             bsum = uv ? b_hh[2 * H + unit] : 0.0f;
            basev[u][r] = gs * bsum;
        }

    // ================= phase-2 identity: one triple per lane =================
    const int  gb = wv / 3;                 // batch 0..3 (wave-uniform)
    const int  gj = (wv % 3) * 64 + lane;   // unit 0..191
    const bool jv = (gj < H);
    float wrS = jv ? -LOG2E * w_ih[gj]              : 0.0f;
    float wzS = jv ? -LOG2E * w_ih[H + gj]          : 0.0f;
    float wnS = jv ?  2.0f * LOG2E * w_ih[2 * H + gj] : 0.0f;
    float bnI = jv ?  2.0f * LOG2E * b_ih[2 * H + gj] : 0.0f;
    // h-frag slot for this lane's quad (leader lane&3==0 writes 4 units)
    const int hoff  = (gj >> 6) * FRAGB + (((gj >> 4) & 3) * 16 + gb) * 16 + (gj & 15);
    const int rbase = lane * 16;

    float h = 0.0f;

    auto step = [&](const char* rb, char* wb, int t) {
        // ---------- phase 1: MFMA + preact publish ----------
        intx4 bf[KT3];
        #pragma unroll
        for (int kt = 0; kt < KT3; ++kt)
            bf[kt] = *(const intx4*)(rb + kt * FRAGB + rbase);
        intx4 acc[3] = {{0,0,0,0}, {0,0,0,0}, {0,0,0,0}};
        #pragma unroll
        for (int kt = 0; kt < KT3; ++kt) {
            acc[0] = __builtin_amdgcn_mfma_i32_16x16x64_i8(afr[0][kt], bf[kt], acc[0], 0, 0, 0);
            acc[1] = __builtin_amdgcn_mfma_i32_16x16x64_i8(afr[1][kt], bf[kt], acc[1], 0, 0, 0);
            acc[2] = __builtin_amdgcn_mfma_i32_16x16x64_i8(afr[2][kt], bf[kt], acc[2], 0, 0, 0);
        }
        if (col < BB) {
            #pragma unroll
            for (int u = 0; u < 3; ++u) {
                floatx4 pv;
                #pragma unroll
                for (int r = 0; r < 4; ++r)
                    pv[r] = fmaf((float)acc[u][r], dqv[u][r], basev[u][r]);
                *(floatx4*)&pre_s[(g * BB + col) * PST + (tg * 3 + u) * 16 + q * 4] = pv;
            }
        }
        __syncthreads();

        // ---------- phase 2: gates (1 triple/lane) ----------
        float pR = pre_s[(0 * BB + gb) * PST + gj];
        float pZ = pre_s[(1 * BB + gb) * PST + gj];
        float pN = pre_s[(2 * BB + gb) * PST + gj];
        float xv = x_s[gb * T_LEN + t];

        float er = exp2_fast(fmaf(xv, wrS, pR));
        float ez = exp2hw(fminf(fmaf(xv, wzS, pZ), 14.0f));
        float dR = 1.0f + er, dZ = 1.0f + ez;
        float qq = rcpf(dR * dZ);
        float rr = qq * dZ, zz = qq * dR;
        float gn = fmaf(rr, pN, fmaf(xv, wnS, bnI));
        float en = exp2hw(fminf(gn, 30.0f));
        float nn = fmaf(-2.0f, rcpf(1.0f + en), 1.0f);  // tanh
        h = fmaf(zz, h - nn, nn);                        // |h|<1

        int iq  = (int)rintf(h * 127.0f);
        int v32 = jv ? (iq & 255) : 0;
        // DPP quad-pack: 4 consecutive lanes' bytes -> leader's b32
        int u1  = __builtin_amdgcn_update_dpp(0, v32, 0xB1, 0xF, 0xF, true); // qp[1,0,3,2]
        int p01 = __builtin_amdgcn_perm(u1, v32, 0x05010400);                // [0,u1.b1,u1.b0,v.b0]
        int u2  = __builtin_amdgcn_update_dpp(0, p01, 0x4E, 0xF, 0xF, true); // qp[2,3,0,1]
        int pq  = __builtin_amdgcn_perm(u2, p01, 0x05040100);                // bytes j0..j0+3
        if ((lane & 3) == 0)
            *(int*)(wb + (hoff & ~15) + (gj & 15)) = pq;   // hoff already dword-aligned for leader
        __syncthreads();
    };

    char* buf0 = hfr_s;
    char* buf1 = hfr_s + KT3 * FRAGB;
    for (int t = 0; t < T_LEN; t += 2) {
        step(buf0, buf1, t);
        step(buf1, buf0, t + 1);
    }

    // ---- final FC: publish h (f32) then 40 lanes reduce ----
    pre_s[gb * PST + gj] = h;
    __syncthreads();
    if (tid < BB * 10) {
        int bb = tid / 10, c = tid % 10;
        float acc = b_fc[c];
        for (int k = 0; k < H; ++k)
            acc = fmaf(pre_s[bb * PST + k], w_fc[c * H + k], acc);
        out[(b0 + bb) * 10 + c] = acc;
    }
}

extern "C" void kernel_launch(void* const* d_in, const int* in_sizes, int n_in,
                              void* d_out, int out_size, void* d_ws, size_t ws_size,
                              hipStream_t stream) {
    const float* x    = (const float*)d_in[0];
    const float* w_ih = (const float*)d_in[1];
    const float* w_hh = (const float*)d_in[2];
    const float* b_ih = (const float*)d_in[3];
    const float* b_hh = (const float*)d_in[4];
    const float* w_fc = (const float*)d_in[5];
    const float* b_fc = (const float*)d_in[6];
    float* out = (float*)d_out;

    gru_i8<<<NBLK, NTHR, 0, stream>>>(x, w_ih, w_hh, b_ih, b_hh, w_fc, b_fc, out);
}

// Round 12
// 839.016 us; speedup vs baseline: 1.2294x; 1.2294x over previous
//
#include <hip/hip_runtime.h>

#define H 181
#define T_LEN 1024
#define BB 4             // batch rows per block
#define NBLK 256         // 256 * 4 = 1024; one block per CU (LDS-pinned)
#define NTHR 768         // 12 waves, 3 per SIMD
#define KT3 3            // k-tiles of 64 -> 192 >= 181
#define FRAGB 1024       // bytes per kt fragment (64 lanes x 16 B)
#define PST 192          // unit stride (wsc, FC)
#define PST2 200         // preact stride in halfs: publish banks exactly 2-way (free)

typedef __attribute__((ext_vector_type(4))) int   intx4;
typedef __attribute__((ext_vector_type(4))) float floatx4;

#define LOG2E 1.4426950408889634f
// Schraudolph exp2 (balanced sawtooth, |rel err| <= ~3%), clamped to [-20,14]
#define SCH_C  1064992506.0f
#define SCH_LO 897220352.0f
#define SCH_HI 1182433024.0f

__device__ __forceinline__ float exp2_fast(float g) {
    float s = fmaf(g, 8388608.0f, SCH_C);
    s = fminf(fmaxf(s, SCH_LO), SCH_HI);
    return __uint_as_float((unsigned)s);
}
__device__ __forceinline__ float rcpf(float x)   { return __builtin_amdgcn_rcpf(x); }
__device__ __forceinline__ float exp2hw(float x) { return __builtin_amdgcn_exp2f(x); }

// 256 persistent blocks x 4 batch (ALL 256 CUs). Two-phase step (R11 structure,
// publish fixed): P1 (wave = gate x 3 unit-tiles) 9 i8 MFMAs -> dequant ->
// f16-packed b64 preact publish at stride 200 halfs (2-way banks = free;
// R11's stride-192 f32 b128 publish was 4-way = 456 conflict cy/step).
// P2 (lane = one (unit,batch) triple): 3 u16 preact reads -> 3 exps
// (r Schraudolph, z/n exact) + 2 rcps -> h update -> i8 quant -> DPP
// quad-pack -> one b32 per 4 lanes into the MFMA B-frag slot.
__launch_bounds__(NTHR, 3)
__global__ void gru_i8(const float* __restrict__ x,
                       const float* __restrict__ w_ih,
                       const float* __restrict__ w_hh,
                       const float* __restrict__ b_ih,
                       const float* __restrict__ b_hh,
                       const float* __restrict__ w_fc,
                       const float* __restrict__ b_fc,
                       float* __restrict__ out) {
    __shared__ __align__(16) char      hfr_s[2 * KT3 * FRAGB];  // 6 KB i8 h dbuf
    __shared__ __align__(16) _Float16  pre_s[3 * BB * PST2];    // 4.7 KB f16 preacts
    __shared__ __align__(16) float     x_s[BB * T_LEN];         // 16 KB x; reused for FC
    __shared__ float wsc_s[3 * PST];                            // w_hh row scales
    __shared__ volatile char pad_s[49152];                      // LDS>80KB: pin 1 block/CU

    const int tid  = threadIdx.x;
    const int wv   = tid >> 6;
    const int lane = tid & 63;
    const int col  = lane & 15;
    const int q    = lane >> 4;
    const int b0   = blockIdx.x * BB;
    if (tid == 0) pad_s[0] = 0;

    // ================= phase-1 identity: gate g, tile group tg =================
    const int g  = wv >> 2;          // 0..2
    const int tg = wv & 3;           // 0..3 ; tiles tg*3+{0,1,2}
    const float gs = (g < 2) ? -LOG2E : 2.0f * LOG2E;

    // ---- A fragments: per-row int8 w_hh, 3 tiles x 3 kt ----
    intx4 afr[3][KT3];
    #pragma unroll
    for (int u = 0; u < 3; ++u) {
        const int  mu = (tg * 3 + u) * 16 + col;
        const bool mv = (mu < H);
        const float* wrow = w_hh + (size_t)(g * H + (mv ? mu : 0)) * H;
        float rm = 0.0f;
        if (mv) for (int k = 0; k < H; ++k) rm = fmaxf(rm, fabsf(wrow[k]));
        float s    = (rm > 1e-30f) ? rm * (1.0f / 127.0f) : 1.0f;
        float invs = 1.0f / s;
        #pragma unroll
        for (int kt = 0; kt < KT3; ++kt) {
            union { signed char c[16]; intx4 v; } uu;
            #pragma unroll
            for (int e = 0; e < 16; ++e) {
                int k = kt * 64 + q * 16 + e;
                float v = (mv && k < H) ? wrow[k] * invs : 0.0f;
                v = fminf(fmaxf(rintf(v), -127.0f), 127.0f);
                uu.c[e] = (signed char)(int)v;
            }
            afr[u][kt] = uu.v;
        }
        if (q == 0) wsc_s[g * PST + mu] = s;
    }

    // ---- stage x; zero h frag buffers ----
    for (int i = tid; i < BB * T_LEN; i += NTHR)
        x_s[i] = x[(size_t)b0 * T_LEN + i];
    {
        int* hz = (int*)hfr_s;
        for (int i = tid; i < 2 * KT3 * FRAGB / 4; i += NTHR) hz[i] = 0;
    }
    __syncthreads();   // wsc_s ready

    // ---- phase-1 dequant constants (per C-lane: 3 tiles x 4 units) ----
    float dqv[3][4], basev[3][4];
    #pragma unroll
    for (int u = 0; u < 3; ++u)
        #pragma unroll
        for (int r = 0; r < 4; ++r) {
            int unit = (tg * 3 + u) * 16 + q * 4 + r;
            bool uv  = (unit < H);
            dqv[u][r] = gs * wsc_s[g * PST + unit] * (1.0f / 127.0f);
            float bsum;
            if (g == 0)      bsum = uv ? (b_ih[unit] + b_hh[unit]) : 0.0f;
            else if (g == 1) bsum = uv ? (b_ih[H + unit] + b_hh[H + unit]) : 0.0f;
            else             bsum = uv ? b_hh[2 * H + unit] : 0.0f;
            basev[u][r] = gs * bsum;
        }

    // ================= phase-2 identity: one triple per lane =================
    const int  gb = wv / 3;                 // batch 0..3 (wave-uniform)
    const int  gj = (wv % 3) * 64 + lane;   // unit 0..191
    const bool jv = (gj < H);
    float wrS = jv ? -LOG2E * w_ih[gj]                : 0.0f;
    float wzS = jv ? -LOG2E * w_ih[H + gj]            : 0.0f;
    float wnS = jv ?  2.0f * LOG2E * w_ih[2 * H + gj] : 0.0f;
    float bnI = jv ?  2.0f * LOG2E * b_ih[2 * H + gj] : 0.0f;
    // h-frag slot for this lane's quad (leader lane&3==0 writes 4 units)
    const int hoff  = (gj >> 6) * FRAGB + (((gj >> 4) & 3) * 16 + gb) * 16 + (gj & 15);
    const int rbase = lane * 16;

    float h = 0.0f;

    auto step = [&](const char* rb, char* wb, int t) {
        // ---------- phase 1: MFMA + dequant + f16 preact publish ----------
        intx4 bf[KT3];
        #pragma unroll
        for (int kt = 0; kt < KT3; ++kt)
            bf[kt] = *(const intx4*)(rb + kt * FRAGB + rbase);
        intx4 acc[3] = {{0,0,0,0}, {0,0,0,0}, {0,0,0,0}};
        #pragma unroll
        for (int kt = 0; kt < KT3; ++kt) {
            acc[0] = __builtin_amdgcn_mfma_i32_16x16x64_i8(afr[0][kt], bf[kt], acc[0], 0, 0, 0);
            acc[1] = __builtin_amdgcn_mfma_i32_16x16x64_i8(afr[1][kt], bf[kt], acc[1], 0, 0, 0);
            acc[2] = __builtin_amdgcn_mfma_i32_16x16x64_i8(afr[2][kt], bf[kt], acc[2], 0, 0, 0);
        }
        if (col < BB) {
            #pragma unroll
            for (int u = 0; u < 3; ++u) {
                float p0 = fmaf((float)acc[u][0], dqv[u][0], basev[u][0]);
                float p1 = fmaf((float)acc[u][1], dqv[u][1], basev[u][1]);
                float p2 = fmaf((float)acc[u][2], dqv[u][2], basev[u][2]);
                float p3 = fmaf((float)acc[u][3], dqv[u][3], basev[u][3]);
                uint2 pk2;
                pk2.x = __builtin_bit_cast(unsigned, __builtin_amdgcn_cvt_pkrtz(p0, p1));
                pk2.y = __builtin_bit_cast(unsigned, __builtin_amdgcn_cvt_pkrtz(p2, p3));
                *(uint2*)&pre_s[(g * BB + col) * PST2 + (tg * 3 + u) * 16 + q * 4] = pk2;
            }
        }
        __syncthreads();

        // ---------- phase 2: gates (1 triple/lane) ----------
        float pR = (float)pre_s[(0 * BB + gb) * PST2 + gj];
        float pZ = (float)pre_s[(1 * BB + gb) * PST2 + gj];
        float pN = (float)pre_s[(2 * BB + gb) * PST2 + gj];
        float xv = x_s[gb * T_LEN + t];

        float er = exp2_fast(fmaf(xv, wrS, pR));
        float ez = exp2hw(fminf(fmaf(xv, wzS, pZ), 14.0f));
        float dR = 1.0f + er, dZ = 1.0f + ez;
        float qq = rcpf(dR * dZ);
        float rr = qq * dZ, zz = qq * dR;
        float gn = fmaf(rr, pN, fmaf(xv, wnS, bnI));
        float en = exp2hw(fminf(gn, 30.0f));
        float nn = fmaf(-2.0f, rcpf(1.0f + en), 1.0f);  // tanh
        h = fmaf(zz, h - nn, nn);                        // |h|<1

        int iq  = (int)rintf(h * 127.0f);
        int v32 = jv ? (iq & 255) : 0;
        // DPP quad-pack: 4 consecutive lanes' bytes -> leader's b32
        int u1  = __builtin_amdgcn_update_dpp(0, v32, 0xB1, 0xF, 0xF, true); // qp[1,0,3,2]
        int p01 = __builtin_amdgcn_perm(u1, v32, 0x05010400);
        int u2  = __builtin_amdgcn_update_dpp(0, p01, 0x4E, 0xF, 0xF, true); // qp[2,3,0,1]
        int pq  = __builtin_amdgcn_perm(u2, p01, 0x05040100);
        if ((lane & 3) == 0)
            *(int*)(wb + (hoff & ~15) + (gj & 15)) = pq;
        __syncthreads();
    };

    char* buf0 = hfr_s;
    char* buf1 = hfr_s + KT3 * FRAGB;
    for (int t = 0; t < T_LEN; t += 2) {
        step(buf0, buf1, t);
        step(buf1, buf0, t + 1);
    }

    // ---- final FC: publish h (f32) into x_s, 40 lanes reduce ----
    __syncthreads();
    x_s[gb * PST + gj] = h;
    __syncthreads();
    if (tid < BB * 10) {
        int bb = tid / 10, c = tid % 10;
        float acc = b_fc[c];
        for (int k = 0; k < H; ++k)
            acc = fmaf(x_s[bb * PST + k], w_fc[c * H + k], acc);
        out[(b0 + bb) * 10 + c] = acc;
    }
}

extern "C" void kernel_launch(void* const* d_in, const int* in_sizes, int n_in,
                              void* d_out, int out_size, void* d_ws, size_t ws_size,
                              hipStream_t stream) {
    const float* x    = (const float*)d_in[0];
    const float* w_ih = (const float*)d_in[1];
    const float* w_hh = (const float*)d_in[2];
    const float* b_ih = (const float*)d_in[3];
    const float* b_hh = (const float*)d_in[4];
    const float* w_fc = (const float*)d_in[5];
    const float* b_fc = (const float*)d_in[6];
    float* out = (float*)d_out;

    gru_i8<<<NBLK, NTHR, 0, stream>>>(x, w_ih, w_hh, b_ih, b_hh, w_fc, b_fc, out);
}